// Round 17
// baseline (96.249 us; speedup 1.0000x reference)
//
#include <hip/hip_runtime.h>

// GridSamplePScan: out[b,t,c] = sum_{k<=t} bilinear(images[b,k,c], wrap(base + cum_t - cum_k))
// B=4, L=32, C=16, H=W=64, fp32 in/out.
//
// R16 = R15 body (63.1us, absmax 0.0625) + per-wave gather-issue
// serialization via s_setprio.
//   Model (3 datapoints): dur responds 1:1 to VALU instr count AND LDS pipe
//   time is fully paid -> pipes SERIALIZED. Mechanism: post-barrier round-
//   robin issue interleaves all 16 waves' ds_reads in the LDS queue, so
//   EVERY wave's reads finish ~end of drain; MACs become a separate burst.
//   Fix: setprio(1) around each wave's 8 gather issues -> priority wave
//   streams its reads back-to-back, completes early, MACs overlap the
//   remaining drain. Coords stay at prio 0 (VALU is per-SIMD parallel).

constexpr int BN = 4, LN = 32, CN = 16, HWn = 4096;
constexpr int FRAME = CN * HWn;
constexpr int PW = 66, PCELLS = PW * PW;                       // 4356 cells
constexpr int CHUNK_B = PCELLS * 16;                           // 69696 B
constexpr size_t TIMG_BYTES = (size_t)BN * LN * 2 * CHUNK_B;   // ~17.8 MB
constexpr size_t CUM_BYTES  = (size_t)BN * LN * HWn * 2 * 4;   // 4 MB

// ---------------------------------------------------------------------------
// images fp32 [B,L,C,H,W] -> fp16 padded [B*L][chh(2)][66][66][8ch] 16B cells.
// ---------------------------------------------------------------------------
__global__ __launch_bounds__(1024) void prep_pad(
        const float* __restrict__ img, float4* __restrict__ timg) {
    const int f = blockIdx.x >> 1, g = blockIdx.x & 1;         // frame, chhalf
    const float* src = img + (size_t)f * FRAME + g * (8 * HWn);
    float4* dst = timg + (size_t)blockIdx.x * PCELLS;
    for (int q = threadIdx.x; q < PCELLS; q += 1024) {
        const int y = q / PW, x = q - y * PW;
        union { float4 f4; _Float16 h[8]; } cell;
        if (y >= 1 && y <= 64 && x >= 1 && x <= 64) {
            const int p = ((y - 1) << 6) + (x - 1);
#pragma unroll
            for (int c = 0; c < 8; ++c)
                cell.h[c] = (_Float16)src[c * HWn + p];        // coalesced
        } else {
            cell.f4 = make_float4(0.f, 0.f, 0.f, 0.f);         // zero pad
        }
        dst[q] = cell.f4;
    }
}

// ---------------------------------------------------------------------------
// cumsum(flows) * 0.5 (exact scaling of the ROUNDED cumsum) -> [B*L][4096]
// ---------------------------------------------------------------------------
__global__ __launch_bounds__(256) void prep_cum(
        const float* __restrict__ flows, float2* __restrict__ cum) {
    const int b = blockIdx.x >> 4;
    const int p = ((blockIdx.x & 15) << 8) + threadIdx.x;
    const float* fl = flows + (size_t)b * (LN * 2 * HWn) + p;
    float cx = 0.f, cy = 0.f;
    for (int l = 0; l < LN; ++l) {              // ascending == jnp.cumsum
        cx += fl[(2 * l) * HWn];
        cy += fl[(2 * l + 1) * HWn];
        cum[(size_t)(b * LN + l) * HWn + p] =
            make_float2(cx * 0.5f, cy * 0.5f);  // exact *0.5
    }
}

// ---------------------------------------------------------------------------
// Guaranteed v_fma_mix_f32: acc += (float)f16(lo/hi of g) * w  (f32 fma)
// ---------------------------------------------------------------------------
__device__ __forceinline__ void mix_lo(float& acc, unsigned g, float w) {
    asm("v_fma_mix_f32 %0, %1, %2, %0 op_sel_hi:[1,0,0]"
        : "+v"(acc) : "v"(g), "v"(w));
}
__device__ __forceinline__ void mix_hi(float& acc, unsigned g, float w) {
    asm("v_fma_mix_f32 %0, %1, %2, %0 op_sel:[1,0,0] op_sel_hi:[1,0,0]"
        : "+v"(acc) : "v"(g), "v"(w));
}
__device__ __forceinline__ void mac8(float* __restrict__ acc, uint4 g, float w) {
    mix_lo(acc[0], g.x, w); mix_hi(acc[1], g.x, w);
    mix_lo(acc[2], g.y, w); mix_hi(acc[3], g.y, w);
    mix_lo(acc[4], g.z, w); mix_hi(acc[5], g.z, w);
    mix_lo(acc[6], g.w, w); mix_hi(acc[7], g.w, w);
}

// ---------------------------------------------------------------------------
// Coordinate/weight chain (identical math/order to R12/R15 px_step; proven).
// ux = (bxh + dh) + 0.5 : reference association, halved (R12 proof).
// ---------------------------------------------------------------------------
struct Cw { int off; float w00, w10, w01, w11; };

__device__ __forceinline__ Cw px_coord(float2 ct, float2 ck,
                                       float bxh, float byh) {
    Cw r;
    const float ux = (bxh + (ct.x - ck.x)) + 0.5f;  // ref add order, halved
    const float uy = (byh + (ct.y - ck.y)) + 0.5f;
    const float fx = ux - floorf(ux);               // [0,1)
    const float fy = uy - floorf(uy);
    const float ixp = fmaf(fx, 64.0f, 0.5f);        // [0.5, 64.5)
    const float iyp = fmaf(fy, 64.0f, 0.5f);
    const float xf = floorf(ixp), yf = floorf(iyp);
    const int x0p = (int)xf, y0p = (int)yf;         // [0, 64]
    const float wx1 = ixp - xf, wy1 = iyp - yf;
    const float wx0 = 1.0f - wx1, wy0 = 1.0f - wy1;
    r.w00 = wx0 * wy0; r.w10 = wx1 * wy0;
    r.w01 = wx0 * wy1; r.w11 = wx1 * wy1;
    r.off = y0p * PW + x0p;
    return r;
}

// ---------------------------------------------------------------------------
// 256 blocks x 1024 thr (1/CU). Block = (b, chh | pair, pxh); thread: 2 px,
// 8 ch, 2 t-phases (triangle-paired: 33 uniform k-iters). R7/R12 schedule.
// ---------------------------------------------------------------------------
__global__ __launch_bounds__(1024, 4) void gsps_lds(
        const float2* __restrict__ cum,
        const char* __restrict__ timg,
        float* __restrict__ out) {
    extern __shared__ char smem[];              // 2 x 69696 B double buffer
    const int bid = blockIdx.x;                 // 256 blocks
    const int xs  = bid & 7;                    // XCD slot
    const int b   = xs >> 1;                    // batch pinned to XCD pair
    const int chh = xs & 1;                     // chh pinned to ONE XCD
    const int seq = bid >> 3;
    const int pair = seq & 15;
    const int pxh  = seq >> 4;                  // pxh-siblings same XCD
    const int tid  = threadIdx.x;
    const int t1 = 31 - pair;                   // heavy phase t
    const int t2 = pair;                        // light phase t

    const int px0 = (pxh << 11) + tid;
    const int px1 = px0 + 1024;
    // bxh = base_x/2 = (w+0.5)*2^-6 - 0.5   (both terms exact, diff exact)
    const float bx0 = ((float)(px0 & 63) + 0.5f) * 0.015625f - 0.5f;
    const float by0 = ((float)(px0 >> 6) + 0.5f) * 0.015625f - 0.5f;
    const float bx1 = ((float)(px1 & 63) + 0.5f) * 0.015625f - 0.5f;
    const float by1 = ((float)(px1 >> 6) + 0.5f) * 0.015625f - 0.5f;

    const float2* cb = cum + (size_t)b * (LN * HWn);
    // chunk base for (b, k, chh): ((b*32 + k)*2 + chh) * CHUNK_B
    const size_t chunk0 = ((size_t)b * LN * 2 + chh) * CHUNK_B;
    const unsigned wbase = (unsigned)(tid & ~63) << 4;   // wave-uniform

    // LDS dest: wave-uniform base (+ HW lane*16); global src per-lane.
#define STAGE(KK, BUF) do {                                                   \
    const char* gsrc = timg + chunk0 + (size_t)(KK) * (2 * CHUNK_B);          \
    char* lbase = smem + (BUF) * CHUNK_B + wbase;                             \
    _Pragma("unroll")                                                         \
    for (int j = 0; j < 4; ++j) {                                             \
        __builtin_amdgcn_global_load_lds(                                     \
            (const __attribute__((address_space(1))) void*)                  \
                (gsrc + (j * 16384 + tid * 16)),                              \
            (__attribute__((address_space(3))) void*)(lbase + j * 16384),    \
            16, 0, 0);                                                        \
    }                                                                         \
    if (tid < PCELLS - 4096) {  /* tail cells 4096..4355 */                   \
        __builtin_amdgcn_global_load_lds(                                     \
            (const __attribute__((address_space(1))) void*)                  \
                (gsrc + (65536 + tid * 16)),                                  \
            (__attribute__((address_space(3))) void*)(lbase + 65536),        \
            16, 0, 0);                                                        \
    }                                                                         \
} while (0)

    float acc0[8] = {0}, acc1[8] = {0};
    float2 ct0 = make_float2(0.f, 0.f), ct1 = ct0;
    float2 ckp0 = cb[px0], ckp1 = cb[px1];      // ck prefetch for iter 0

    STAGE(0, 0);                                // prologue: frame 0 -> buf0

    for (int i = 0; i < 33; ++i) {
        const bool ph2 = (i > t1);
        const int k = ph2 ? (i - t1 - 1) : i;
        const int t = ph2 ? t2 : t1;

        // barrier drains vmcnt(0): STAGE(i) complete; buf^1 readers done
        __syncthreads();
        if (i < 32) {                           // issue next DMA now; it
            const int kn = (i + 1 > t1) ? (i - t1) : (i + 1);
            STAGE(kn, (i + 1) & 1);             // drains at NEXT barrier
        }

        const float2 ck0 = ckp0, ck1 = ckp1;
        if (i < 32) {                           // prefetch next ck pair
            const int kn = (i + 1 > t1) ? (i - t1) : (i + 1);
            ckp0 = cb[kn * HWn + px0];
            ckp1 = cb[kn * HWn + px1];
        }
        if (k == 0) {                           // phase start
            ct0 = cb[t * HWn + px0];
            ct1 = cb[t * HWn + px1];
#pragma unroll
            for (int c = 0; c < 8; ++c) { acc0[c] = 0.f; acc1[c] = 0.f; }
        }

        // ---- coords (normal prio: VALU is per-SIMD parallel)
        const Cw cA = px_coord(ct0, ck0, bx0, by0);
        const Cw cB = px_coord(ct1, ck1, bx1, by1);
        const uint4* fr = (const uint4*)(smem + (i & 1) * CHUNK_B);

        // ---- gather issue at high prio: this wave streams its 8 reads
        // back-to-back instead of round-robin interleaving with 15 others,
        // so ITS reads complete early and its MACs overlap the drain.
        __builtin_amdgcn_s_setprio(1);
        const uint4 a00 = fr[cA.off],      a10 = fr[cA.off + 1];
        const uint4 a01 = fr[cA.off + PW], a11 = fr[cA.off + PW + 1];
        const uint4 b00 = fr[cB.off],      b10 = fr[cB.off + 1];
        const uint4 b01 = fr[cB.off + PW], b11 = fr[cB.off + PW + 1];
        __builtin_amdgcn_sched_barrier(0);      // pin loads above prio drop
        __builtin_amdgcn_s_setprio(0);

        // ---- MACs (128x v_fma_mix_f32)
        mac8(acc0, a00, cA.w00); mac8(acc0, a10, cA.w10);
        mac8(acc0, a01, cA.w01); mac8(acc0, a11, cA.w11);
        mac8(acc1, b00, cB.w00); mac8(acc1, b10, cB.w10);
        mac8(acc1, b01, cB.w01); mac8(acc1, b11, cB.w11);

        if (k == t) {                           // phase end: write out
            float* op = out + ((size_t)(b * LN + t) * CN + chh * 8) * HWn;
#pragma unroll
            for (int c = 0; c < 8; ++c) {
                op[c * HWn + px0] = acc0[c];
                op[c * HWn + px1] = acc1[c];
            }
        }
    }
#undef STAGE
}

// ---------------------------------------------------------------------------
// Fallback (ws too small / attr fails): direct fp32 gather (proven R1 kernel).
// ---------------------------------------------------------------------------
__global__ __launch_bounds__(256) void gsps_slow(
        const float* __restrict__ flows,
        const float* __restrict__ img,
        float* __restrict__ out) {
    const int bi = blockIdx.x;
    const int tile = bi & 15;
    const int rest = bi >> 4;
    const int t = 31 - (rest & 31);
    const int b = rest >> 5;
    const int p = (tile << 8) + threadIdx.x;
    const int h = p >> 6, w = p & 63;
    const float base_x = ((float)w + 0.5f) * 0.03125f - 1.0f;
    const float base_y = ((float)h + 0.5f) * 0.03125f - 1.0f;
    const float* fl = flows + (size_t)b * (LN * 2 * HWn) + p;

    float ctx = 0.f, cty = 0.f;
    for (int j = 0; j <= t; ++j) { ctx += fl[(2*j)*HWn]; cty += fl[(2*j+1)*HWn]; }

    float acc[16];
#pragma unroll
    for (int c = 0; c < 16; ++c) acc[c] = 0.f;

    float ckx = 0.f, cky = 0.f;
    for (int k = 0; k <= t; ++k) {
        ckx += fl[(2*k)*HWn]; cky += fl[(2*k+1)*HWn];
        float vx = (base_x + (ctx - ckx)) + 1.0f;
        float vy = (base_y + (cty - cky)) + 1.0f;
        float mx = vx - 2.0f * floorf(vx * 0.5f);
        float my = vy - 2.0f * floorf(vy * 0.5f);
        const float ix = ((mx - 1.0f) + 1.0f) * 32.0f - 0.5f;
        const float iy = ((my - 1.0f) + 1.0f) * 32.0f - 0.5f;
        const float x0f = floorf(ix), y0f = floorf(iy);
        const int x0 = (int)x0f, y0 = (int)y0f;
        const float wx1 = ix - x0f, wy1 = iy - y0f;
        const float wx0 = 1.0f - wx1, wy0 = 1.0f - wy1;
        const int x1 = x0 + 1, y1 = y0 + 1;
        const float fx0 = (x0 >= 0) ? 1.0f : 0.0f;
        const float fx1 = (x1 <= 63) ? 1.0f : 0.0f;
        const float fy0 = (y0 >= 0) ? 1.0f : 0.0f;
        const float fy1 = (y1 <= 63) ? 1.0f : 0.0f;
        const int x0c = (x0 < 0) ? 0 : x0, x1c = (x1 > 63) ? 63 : x1;
        const int y0c = (y0 < 0) ? 0 : y0, y1c = (y1 > 63) ? 63 : y1;
        const float w00 = (wx0*wy0)*(fx0*fy0), w10 = (wx1*wy0)*(fx1*fy0);
        const float w01 = (wx0*wy1)*(fx0*fy1), w11 = (wx1*wy1)*(fx1*fy1);
        const float* frm = img + (size_t)(b * LN + k) * FRAME;
        const int i00 = (y0c<<6)+x0c, i10 = (y0c<<6)+x1c;
        const int i01 = (y1c<<6)+x0c, i11 = (y1c<<6)+x1c;
#pragma unroll
        for (int c = 0; c < 16; ++c) {
            const float* pl = frm + c * HWn;
            acc[c] += ((w00*pl[i00] + w10*pl[i10]) + w01*pl[i01]) + w11*pl[i11];
        }
    }
    float* op = out + (size_t)(b * LN + t) * FRAME + p;
#pragma unroll
    for (int c = 0; c < 16; ++c) op[c * HWn] = acc[c];
}

extern "C" void kernel_launch(void* const* d_in, const int* in_sizes, int n_in,
                              void* d_out, int out_size, void* d_ws, size_t ws_size,
                              hipStream_t stream) {
    const float* flows  = (const float*)d_in[0];   // [4,32,2,64,64] f32
    const float* images = (const float*)d_in[1];   // [4,32,16,64,64] f32
    float* out = (float*)d_out;                    // [4,32,16,64,64] f32

    bool fast = (ws_size >= TIMG_BYTES + CUM_BYTES);
    if (fast) {
        hipError_t e = hipFuncSetAttribute(
            reinterpret_cast<const void*>(&gsps_lds),
            hipFuncAttributeMaxDynamicSharedMemorySize, 2 * CHUNK_B);
        if (e != hipSuccess) fast = false;
    }
    if (fast) {
        float4* timg = (float4*)d_ws;
        float2* cumw = (float2*)((char*)d_ws + TIMG_BYTES);
        prep_pad<<<BN * LN * 2, 1024, 0, stream>>>(images, timg);
        prep_cum<<<BN * 16, 256, 0, stream>>>(flows, cumw);
        gsps_lds<<<256, 1024, 2 * CHUNK_B, stream>>>(
            cumw, (const char*)timg, out);
    } else {
        gsps_slow<<<BN * LN * 16, 256, 0, stream>>>(flows, images, out);
    }
}

// Round 18
// 74.621 us; speedup vs baseline: 1.2898x; 1.2898x over previous
//
#include <hip/hip_runtime.h>

// GridSamplePScan: out[b,t,c] = sum_{k<=t} bilinear(images[b,k,c], wrap(base + cum_t - cum_k))
// B=4, L=32, C=16, H=W=64, fp32 in/out.
//
// R17 = R15 body (63.1us, absmax 0.0625) + STAGE issued AFTER the gathers.
//   Diagnosis: SQ_LDS_BANK_CONFLICT = 8.32M (invariant R7..R16) = 985cy/iter
//   = 22% of the iteration. Read streams are provably bank-balanced (lanes
//   sample same row, consecutive x) -> conflicts must be ds_read vs
//   global_load_lds-DMA write collisions: both issued back-to-back post-
//   barrier, fighting for the 32 banks through the whole read window.
//   Fix: issue the 8 gather ds_reads FIRST, then the DMA; the write stream
//   lands during the ~3000cy MAC phase when banks are idle, and still
//   completes before the next barrier's vmcnt(0) drain.
//   (setprio from R16 dropped: measured null.)

constexpr int BN = 4, LN = 32, CN = 16, HWn = 4096;
constexpr int FRAME = CN * HWn;
constexpr int PW = 66, PCELLS = PW * PW;                       // 4356 cells
constexpr int CHUNK_B = PCELLS * 16;                           // 69696 B
constexpr size_t TIMG_BYTES = (size_t)BN * LN * 2 * CHUNK_B;   // ~17.8 MB
constexpr size_t CUM_BYTES  = (size_t)BN * LN * HWn * 2 * 4;   // 4 MB

// ---------------------------------------------------------------------------
// images fp32 [B,L,C,H,W] -> fp16 padded [B*L][chh(2)][66][66][8ch] 16B cells.
// ---------------------------------------------------------------------------
__global__ __launch_bounds__(1024) void prep_pad(
        const float* __restrict__ img, float4* __restrict__ timg) {
    const int f = blockIdx.x >> 1, g = blockIdx.x & 1;         // frame, chhalf
    const float* src = img + (size_t)f * FRAME + g * (8 * HWn);
    float4* dst = timg + (size_t)blockIdx.x * PCELLS;
    for (int q = threadIdx.x; q < PCELLS; q += 1024) {
        const int y = q / PW, x = q - y * PW;
        union { float4 f4; _Float16 h[8]; } cell;
        if (y >= 1 && y <= 64 && x >= 1 && x <= 64) {
            const int p = ((y - 1) << 6) + (x - 1);
#pragma unroll
            for (int c = 0; c < 8; ++c)
                cell.h[c] = (_Float16)src[c * HWn + p];        // coalesced
        } else {
            cell.f4 = make_float4(0.f, 0.f, 0.f, 0.f);         // zero pad
        }
        dst[q] = cell.f4;
    }
}

// ---------------------------------------------------------------------------
// cumsum(flows) * 0.5 (exact scaling of the ROUNDED cumsum) -> [B*L][4096]
// ---------------------------------------------------------------------------
__global__ __launch_bounds__(256) void prep_cum(
        const float* __restrict__ flows, float2* __restrict__ cum) {
    const int b = blockIdx.x >> 4;
    const int p = ((blockIdx.x & 15) << 8) + threadIdx.x;
    const float* fl = flows + (size_t)b * (LN * 2 * HWn) + p;
    float cx = 0.f, cy = 0.f;
    for (int l = 0; l < LN; ++l) {              // ascending == jnp.cumsum
        cx += fl[(2 * l) * HWn];
        cy += fl[(2 * l + 1) * HWn];
        cum[(size_t)(b * LN + l) * HWn + p] =
            make_float2(cx * 0.5f, cy * 0.5f);  // exact *0.5
    }
}

// ---------------------------------------------------------------------------
// Guaranteed v_fma_mix_f32: acc += (float)f16(lo/hi of g) * w  (f32 fma)
// ---------------------------------------------------------------------------
__device__ __forceinline__ void mix_lo(float& acc, unsigned g, float w) {
    asm("v_fma_mix_f32 %0, %1, %2, %0 op_sel_hi:[1,0,0]"
        : "+v"(acc) : "v"(g), "v"(w));
}
__device__ __forceinline__ void mix_hi(float& acc, unsigned g, float w) {
    asm("v_fma_mix_f32 %0, %1, %2, %0 op_sel:[1,0,0] op_sel_hi:[1,0,0]"
        : "+v"(acc) : "v"(g), "v"(w));
}
__device__ __forceinline__ void mac8(float* __restrict__ acc, uint4 g, float w) {
    mix_lo(acc[0], g.x, w); mix_hi(acc[1], g.x, w);
    mix_lo(acc[2], g.y, w); mix_hi(acc[3], g.y, w);
    mix_lo(acc[4], g.z, w); mix_hi(acc[5], g.z, w);
    mix_lo(acc[6], g.w, w); mix_hi(acc[7], g.w, w);
}

// ---------------------------------------------------------------------------
// Coordinate/weight chain (identical math/order to R12/R15; proven).
// ux = (bxh + dh) + 0.5 : reference association, halved (R12 proof).
// ---------------------------------------------------------------------------
struct Cw { int off; float w00, w10, w01, w11; };

__device__ __forceinline__ Cw px_coord(float2 ct, float2 ck,
                                       float bxh, float byh) {
    Cw r;
    const float ux = (bxh + (ct.x - ck.x)) + 0.5f;  // ref add order, halved
    const float uy = (byh + (ct.y - ck.y)) + 0.5f;
    const float fx = ux - floorf(ux);               // [0,1)
    const float fy = uy - floorf(uy);
    const float ixp = fmaf(fx, 64.0f, 0.5f);        // [0.5, 64.5)
    const float iyp = fmaf(fy, 64.0f, 0.5f);
    const float xf = floorf(ixp), yf = floorf(iyp);
    const int x0p = (int)xf, y0p = (int)yf;         // [0, 64]
    const float wx1 = ixp - xf, wy1 = iyp - yf;
    const float wx0 = 1.0f - wx1, wy0 = 1.0f - wy1;
    r.w00 = wx0 * wy0; r.w10 = wx1 * wy0;
    r.w01 = wx0 * wy1; r.w11 = wx1 * wy1;
    r.off = y0p * PW + x0p;
    return r;
}

// ---------------------------------------------------------------------------
// 256 blocks x 1024 thr (1/CU). Block = (b, chh | pair, pxh); thread: 2 px,
// 8 ch, 2 t-phases (triangle-paired: 33 uniform k-iters). R7/R12 schedule,
// but DMA issued AFTER the gather reads (bank decontention).
// ---------------------------------------------------------------------------
__global__ __launch_bounds__(1024, 4) void gsps_lds(
        const float2* __restrict__ cum,
        const char* __restrict__ timg,
        float* __restrict__ out) {
    extern __shared__ char smem[];              // 2 x 69696 B double buffer
    const int bid = blockIdx.x;                 // 256 blocks
    const int xs  = bid & 7;                    // XCD slot
    const int b   = xs >> 1;                    // batch pinned to XCD pair
    const int chh = xs & 1;                     // chh pinned to ONE XCD
    const int seq = bid >> 3;
    const int pair = seq & 15;
    const int pxh  = seq >> 4;                  // pxh-siblings same XCD
    const int tid  = threadIdx.x;
    const int t1 = 31 - pair;                   // heavy phase t
    const int t2 = pair;                        // light phase t

    const int px0 = (pxh << 11) + tid;
    const int px1 = px0 + 1024;
    // bxh = base_x/2 = (w+0.5)*2^-6 - 0.5   (both terms exact, diff exact)
    const float bx0 = ((float)(px0 & 63) + 0.5f) * 0.015625f - 0.5f;
    const float by0 = ((float)(px0 >> 6) + 0.5f) * 0.015625f - 0.5f;
    const float bx1 = ((float)(px1 & 63) + 0.5f) * 0.015625f - 0.5f;
    const float by1 = ((float)(px1 >> 6) + 0.5f) * 0.015625f - 0.5f;

    const float2* cb = cum + (size_t)b * (LN * HWn);
    // chunk base for (b, k, chh): ((b*32 + k)*2 + chh) * CHUNK_B
    const size_t chunk0 = ((size_t)b * LN * 2 + chh) * CHUNK_B;
    const unsigned wbase = (unsigned)(tid & ~63) << 4;   // wave-uniform

    // LDS dest: wave-uniform base (+ HW lane*16); global src per-lane.
#define STAGE(KK, BUF) do {                                                   \
    const char* gsrc = timg + chunk0 + (size_t)(KK) * (2 * CHUNK_B);          \
    char* lbase = smem + (BUF) * CHUNK_B + wbase;                             \
    _Pragma("unroll")                                                         \
    for (int j = 0; j < 4; ++j) {                                             \
        __builtin_amdgcn_global_load_lds(                                     \
            (const __attribute__((address_space(1))) void*)                  \
                (gsrc + (j * 16384 + tid * 16)),                              \
            (__attribute__((address_space(3))) void*)(lbase + j * 16384),    \
            16, 0, 0);                                                        \
    }                                                                         \
    if (tid < PCELLS - 4096) {  /* tail cells 4096..4355 */                   \
        __builtin_amdgcn_global_load_lds(                                     \
            (const __attribute__((address_space(1))) void*)                  \
                (gsrc + (65536 + tid * 16)),                                  \
            (__attribute__((address_space(3))) void*)(lbase + 65536),        \
            16, 0, 0);                                                        \
    }                                                                         \
} while (0)

    float acc0[8] = {0}, acc1[8] = {0};
    float2 ct0 = make_float2(0.f, 0.f), ct1 = ct0;
    float2 ckp0 = cb[px0], ckp1 = cb[px1];      // ck prefetch for iter 0

    STAGE(0, 0);                                // prologue: frame 0 -> buf0

    for (int i = 0; i < 33; ++i) {
        const bool ph2 = (i > t1);
        const int k = ph2 ? (i - t1 - 1) : i;
        const int t = ph2 ? t2 : t1;

        // barrier drains vmcnt(0): STAGE(i) complete; buf^1 readers done
        __syncthreads();

        const float2 ck0 = ckp0, ck1 = ckp1;
        if (i < 32) {                           // prefetch next ck pair
            const int kn = (i + 1 > t1) ? (i - t1) : (i + 1);
            ckp0 = cb[kn * HWn + px0];
            ckp1 = cb[kn * HWn + px1];
        }
        if (k == 0) {                           // phase start
            ct0 = cb[t * HWn + px0];
            ct1 = cb[t * HWn + px1];
#pragma unroll
            for (int c = 0; c < 8; ++c) { acc0[c] = 0.f; acc1[c] = 0.f; }
        }

        // ---- coords + gather ds_reads FIRST (banks uncontended)
        const Cw cA = px_coord(ct0, ck0, bx0, by0);
        const Cw cB = px_coord(ct1, ck1, bx1, by1);
        const uint4* fr = (const uint4*)(smem + (i & 1) * CHUNK_B);
        const uint4 a00 = fr[cA.off],      a10 = fr[cA.off + 1];
        const uint4 a01 = fr[cA.off + PW], a11 = fr[cA.off + PW + 1];
        const uint4 b00 = fr[cB.off],      b10 = fr[cB.off + 1];
        const uint4 b01 = fr[cB.off + PW], b11 = fr[cB.off + PW + 1];

        // ---- THEN issue next-frame DMA: its LDS writes land during the
        // MAC phase (banks idle), not during the gather read window.
        if (i < 32) {
            const int kn = (i + 1 > t1) ? (i - t1) : (i + 1);
            STAGE(kn, (i + 1) & 1);             // drains at NEXT barrier
        }

        // ---- MACs (128x v_fma_mix_f32)
        mac8(acc0, a00, cA.w00); mac8(acc0, a10, cA.w10);
        mac8(acc0, a01, cA.w01); mac8(acc0, a11, cA.w11);
        mac8(acc1, b00, cB.w00); mac8(acc1, b10, cB.w10);
        mac8(acc1, b01, cB.w01); mac8(acc1, b11, cB.w11);

        if (k == t) {                           // phase end: write out
            float* op = out + ((size_t)(b * LN + t) * CN + chh * 8) * HWn;
#pragma unroll
            for (int c = 0; c < 8; ++c) {
                op[c * HWn + px0] = acc0[c];
                op[c * HWn + px1] = acc1[c];
            }
        }
    }
#undef STAGE
}

// ---------------------------------------------------------------------------
// Fallback (ws too small / attr fails): direct fp32 gather (proven R1 kernel).
// ---------------------------------------------------------------------------
__global__ __launch_bounds__(256) void gsps_slow(
        const float* __restrict__ flows,
        const float* __restrict__ img,
        float* __restrict__ out) {
    const int bi = blockIdx.x;
    const int tile = bi & 15;
    const int rest = bi >> 4;
    const int t = 31 - (rest & 31);
    const int b = rest >> 5;
    const int p = (tile << 8) + threadIdx.x;
    const int h = p >> 6, w = p & 63;
    const float base_x = ((float)w + 0.5f) * 0.03125f - 1.0f;
    const float base_y = ((float)h + 0.5f) * 0.03125f - 1.0f;
    const float* fl = flows + (size_t)b * (LN * 2 * HWn) + p;

    float ctx = 0.f, cty = 0.f;
    for (int j = 0; j <= t; ++j) { ctx += fl[(2*j)*HWn]; cty += fl[(2*j+1)*HWn]; }

    float acc[16];
#pragma unroll
    for (int c = 0; c < 16; ++c) acc[c] = 0.f;

    float ckx = 0.f, cky = 0.f;
    for (int k = 0; k <= t; ++k) {
        ckx += fl[(2*k)*HWn]; cky += fl[(2*k+1)*HWn];
        float vx = (base_x + (ctx - ckx)) + 1.0f;
        float vy = (base_y + (cty - cky)) + 1.0f;
        float mx = vx - 2.0f * floorf(vx * 0.5f);
        float my = vy - 2.0f * floorf(vy * 0.5f);
        const float ix = ((mx - 1.0f) + 1.0f) * 32.0f - 0.5f;
        const float iy = ((my - 1.0f) + 1.0f) * 32.0f - 0.5f;
        const float x0f = floorf(ix), y0f = floorf(iy);
        const int x0 = (int)x0f, y0 = (int)y0f;
        const float wx1 = ix - x0f, wy1 = iy - y0f;
        const float wx0 = 1.0f - wx1, wy0 = 1.0f - wy1;
        const int x1 = x0 + 1, y1 = y0 + 1;
        const float fx0 = (x0 >= 0) ? 1.0f : 0.0f;
        const float fx1 = (x1 <= 63) ? 1.0f : 0.0f;
        const float fy0 = (y0 >= 0) ? 1.0f : 0.0f;
        const float fy1 = (y1 <= 63) ? 1.0f : 0.0f;
        const int x0c = (x0 < 0) ? 0 : x0, x1c = (x1 > 63) ? 63 : x1;
        const int y0c = (y0 < 0) ? 0 : y0, y1c = (y1 > 63) ? 63 : y1;
        const float w00 = (wx0*wy0)*(fx0*fy0), w10 = (wx1*wy0)*(fx1*fy0);
        const float w01 = (wx0*wy1)*(fx0*fy1), w11 = (wx1*wy1)*(fx1*fy1);
        const float* frm = img + (size_t)(b * LN + k) * FRAME;
        const int i00 = (y0c<<6)+x0c, i10 = (y0c<<6)+x1c;
        const int i01 = (y1c<<6)+x0c, i11 = (y1c<<6)+x1c;
#pragma unroll
        for (int c = 0; c < 16; ++c) {
            const float* pl = frm + c * HWn;
            acc[c] += ((w00*pl[i00] + w10*pl[i10]) + w01*pl[i01]) + w11*pl[i11];
        }
    }
    float* op = out + (size_t)(b * LN + t) * FRAME + p;
#pragma unroll
    for (int c = 0; c < 16; ++c) op[c * HWn] = acc[c];
}

extern "C" void kernel_launch(void* const* d_in, const int* in_sizes, int n_in,
                              void* d_out, int out_size, void* d_ws, size_t ws_size,
                              hipStream_t stream) {
    const float* flows  = (const float*)d_in[0];   // [4,32,2,64,64] f32
    const float* images = (const float*)d_in[1];   // [4,32,16,64,64] f32
    float* out = (float*)d_out;                    // [4,32,16,64,64] f32

    bool fast = (ws_size >= TIMG_BYTES + CUM_BYTES);
    if (fast) {
        hipError_t e = hipFuncSetAttribute(
            reinterpret_cast<const void*>(&gsps_lds),
            hipFuncAttributeMaxDynamicSharedMemorySize, 2 * CHUNK_B);
        if (e != hipSuccess) fast = false;
    }
    if (fast) {
        float4* timg = (float4*)d_ws;
        float2* cumw = (float2*)((char*)d_ws + TIMG_BYTES);
        prep_pad<<<BN * LN * 2, 1024, 0, stream>>>(images, timg);
        prep_cum<<<BN * 16, 256, 0, stream>>>(flows, cumw);
        gsps_lds<<<256, 1024, 2 * CHUNK_B, stream>>>(
            cumw, (const char*)timg, out);
    } else {
        gsps_slow<<<BN * LN * 16, 256, 0, stream>>>(flows, images, out);
    }
}

// Round 19
// 74.327 us; speedup vs baseline: 1.2949x; 1.0040x over previous
//
#include <hip/hip_runtime.h>

// GridSamplePScan: out[b,t,c] = sum_{k<=t} bilinear(images[b,k,c], wrap(base + cum_t - cum_k))
// B=4, L=32, C=16, H=W=64, fp32 in/out.
//
// R17 = R15 body (63.1us, absmax 0.0625) + STAGE issued AFTER the gathers.
//   Diagnosis: SQ_LDS_BANK_CONFLICT = 8.32M (invariant R7..R16) = 985cy/iter
//   = 22% of the iteration. Read streams are provably bank-balanced (lanes
//   sample same row, consecutive x) -> conflicts must be ds_read vs
//   global_load_lds-DMA write collisions: both issued back-to-back post-
//   barrier, fighting for the 32 banks through the whole read window.
//   Fix: issue the 8 gather ds_reads FIRST, then the DMA; the write stream
//   lands during the ~3000cy MAC phase when banks are idle, and still
//   completes before the next barrier's vmcnt(0) drain.
//   (setprio from R16 dropped: measured null.)

constexpr int BN = 4, LN = 32, CN = 16, HWn = 4096;
constexpr int FRAME = CN * HWn;
constexpr int PW = 66, PCELLS = PW * PW;                       // 4356 cells
constexpr int CHUNK_B = PCELLS * 16;                           // 69696 B
constexpr size_t TIMG_BYTES = (size_t)BN * LN * 2 * CHUNK_B;   // ~17.8 MB
constexpr size_t CUM_BYTES  = (size_t)BN * LN * HWn * 2 * 4;   // 4 MB

// ---------------------------------------------------------------------------
// images fp32 [B,L,C,H,W] -> fp16 padded [B*L][chh(2)][66][66][8ch] 16B cells.
// ---------------------------------------------------------------------------
__global__ __launch_bounds__(1024) void prep_pad(
        const float* __restrict__ img, float4* __restrict__ timg) {
    const int f = blockIdx.x >> 1, g = blockIdx.x & 1;         // frame, chhalf
    const float* src = img + (size_t)f * FRAME + g * (8 * HWn);
    float4* dst = timg + (size_t)blockIdx.x * PCELLS;
    for (int q = threadIdx.x; q < PCELLS; q += 1024) {
        const int y = q / PW, x = q - y * PW;
        union { float4 f4; _Float16 h[8]; } cell;
        if (y >= 1 && y <= 64 && x >= 1 && x <= 64) {
            const int p = ((y - 1) << 6) + (x - 1);
#pragma unroll
            for (int c = 0; c < 8; ++c)
                cell.h[c] = (_Float16)src[c * HWn + p];        // coalesced
        } else {
            cell.f4 = make_float4(0.f, 0.f, 0.f, 0.f);         // zero pad
        }
        dst[q] = cell.f4;
    }
}

// ---------------------------------------------------------------------------
// cumsum(flows) * 0.5 (exact scaling of the ROUNDED cumsum) -> [B*L][4096]
// ---------------------------------------------------------------------------
__global__ __launch_bounds__(256) void prep_cum(
        const float* __restrict__ flows, float2* __restrict__ cum) {
    const int b = blockIdx.x >> 4;
    const int p = ((blockIdx.x & 15) << 8) + threadIdx.x;
    const float* fl = flows + (size_t)b * (LN * 2 * HWn) + p;
    float cx = 0.f, cy = 0.f;
    for (int l = 0; l < LN; ++l) {              // ascending == jnp.cumsum
        cx += fl[(2 * l) * HWn];
        cy += fl[(2 * l + 1) * HWn];
        cum[(size_t)(b * LN + l) * HWn + p] =
            make_float2(cx * 0.5f, cy * 0.5f);  // exact *0.5
    }
}

// ---------------------------------------------------------------------------
// Guaranteed v_fma_mix_f32: acc += (float)f16(lo/hi of g) * w  (f32 fma)
// ---------------------------------------------------------------------------
__device__ __forceinline__ void mix_lo(float& acc, unsigned g, float w) {
    asm("v_fma_mix_f32 %0, %1, %2, %0 op_sel_hi:[1,0,0]"
        : "+v"(acc) : "v"(g), "v"(w));
}
__device__ __forceinline__ void mix_hi(float& acc, unsigned g, float w) {
    asm("v_fma_mix_f32 %0, %1, %2, %0 op_sel:[1,0,0] op_sel_hi:[1,0,0]"
        : "+v"(acc) : "v"(g), "v"(w));
}
__device__ __forceinline__ void mac8(float* __restrict__ acc, uint4 g, float w) {
    mix_lo(acc[0], g.x, w); mix_hi(acc[1], g.x, w);
    mix_lo(acc[2], g.y, w); mix_hi(acc[3], g.y, w);
    mix_lo(acc[4], g.z, w); mix_hi(acc[5], g.z, w);
    mix_lo(acc[6], g.w, w); mix_hi(acc[7], g.w, w);
}

// ---------------------------------------------------------------------------
// Coordinate/weight chain (identical math/order to R12/R15; proven).
// ux = (bxh + dh) + 0.5 : reference association, halved (R12 proof).
// ---------------------------------------------------------------------------
struct Cw { int off; float w00, w10, w01, w11; };

__device__ __forceinline__ Cw px_coord(float2 ct, float2 ck,
                                       float bxh, float byh) {
    Cw r;
    const float ux = (bxh + (ct.x - ck.x)) + 0.5f;  // ref add order, halved
    const float uy = (byh + (ct.y - ck.y)) + 0.5f;
    const float fx = ux - floorf(ux);               // [0,1)
    const float fy = uy - floorf(uy);
    const float ixp = fmaf(fx, 64.0f, 0.5f);        // [0.5, 64.5)
    const float iyp = fmaf(fy, 64.0f, 0.5f);
    const float xf = floorf(ixp), yf = floorf(iyp);
    const int x0p = (int)xf, y0p = (int)yf;         // [0, 64]
    const float wx1 = ixp - xf, wy1 = iyp - yf;
    const float wx0 = 1.0f - wx1, wy0 = 1.0f - wy1;
    r.w00 = wx0 * wy0; r.w10 = wx1 * wy0;
    r.w01 = wx0 * wy1; r.w11 = wx1 * wy1;
    r.off = y0p * PW + x0p;
    return r;
}

// ---------------------------------------------------------------------------
// 256 blocks x 1024 thr (1/CU). Block = (b, chh | pair, pxh); thread: 2 px,
// 8 ch, 2 t-phases (triangle-paired: 33 uniform k-iters). R7/R12 schedule,
// but DMA issued AFTER the gather reads (bank decontention).
// ---------------------------------------------------------------------------
__global__ __launch_bounds__(1024, 4) void gsps_lds(
        const float2* __restrict__ cum,
        const char* __restrict__ timg,
        float* __restrict__ out) {
    extern __shared__ char smem[];              // 2 x 69696 B double buffer
    const int bid = blockIdx.x;                 // 256 blocks
    const int xs  = bid & 7;                    // XCD slot
    const int b   = xs >> 1;                    // batch pinned to XCD pair
    const int chh = xs & 1;                     // chh pinned to ONE XCD
    const int seq = bid >> 3;
    const int pair = seq & 15;
    const int pxh  = seq >> 4;                  // pxh-siblings same XCD
    const int tid  = threadIdx.x;
    const int t1 = 31 - pair;                   // heavy phase t
    const int t2 = pair;                        // light phase t

    const int px0 = (pxh << 11) + tid;
    const int px1 = px0 + 1024;
    // bxh = base_x/2 = (w+0.5)*2^-6 - 0.5   (both terms exact, diff exact)
    const float bx0 = ((float)(px0 & 63) + 0.5f) * 0.015625f - 0.5f;
    const float by0 = ((float)(px0 >> 6) + 0.5f) * 0.015625f - 0.5f;
    const float bx1 = ((float)(px1 & 63) + 0.5f) * 0.015625f - 0.5f;
    const float by1 = ((float)(px1 >> 6) + 0.5f) * 0.015625f - 0.5f;

    const float2* cb = cum + (size_t)b * (LN * HWn);
    // chunk base for (b, k, chh): ((b*32 + k)*2 + chh) * CHUNK_B
    const size_t chunk0 = ((size_t)b * LN * 2 + chh) * CHUNK_B;
    const unsigned wbase = (unsigned)(tid & ~63) << 4;   // wave-uniform

    // LDS dest: wave-uniform base (+ HW lane*16); global src per-lane.
#define STAGE(KK, BUF) do {                                                   \
    const char* gsrc = timg + chunk0 + (size_t)(KK) * (2 * CHUNK_B);          \
    char* lbase = smem + (BUF) * CHUNK_B + wbase;                             \
    _Pragma("unroll")                                                         \
    for (int j = 0; j < 4; ++j) {                                             \
        __builtin_amdgcn_global_load_lds(                                     \
            (const __attribute__((address_space(1))) void*)                  \
                (gsrc + (j * 16384 + tid * 16)),                              \
            (__attribute__((address_space(3))) void*)(lbase + j * 16384),    \
            16, 0, 0);                                                        \
    }                                                                         \
    if (tid < PCELLS - 4096) {  /* tail cells 4096..4355 */                   \
        __builtin_amdgcn_global_load_lds(                                     \
            (const __attribute__((address_space(1))) void*)                  \
                (gsrc + (65536 + tid * 16)),                                  \
            (__attribute__((address_space(3))) void*)(lbase + 65536),        \
            16, 0, 0);                                                        \
    }                                                                         \
} while (0)

    float acc0[8] = {0}, acc1[8] = {0};
    float2 ct0 = make_float2(0.f, 0.f), ct1 = ct0;
    float2 ckp0 = cb[px0], ckp1 = cb[px1];      // ck prefetch for iter 0

    STAGE(0, 0);                                // prologue: frame 0 -> buf0

    for (int i = 0; i < 33; ++i) {
        const bool ph2 = (i > t1);
        const int k = ph2 ? (i - t1 - 1) : i;
        const int t = ph2 ? t2 : t1;

        // barrier drains vmcnt(0): STAGE(i) complete; buf^1 readers done
        __syncthreads();

        const float2 ck0 = ckp0, ck1 = ckp1;
        if (i < 32) {                           // prefetch next ck pair
            const int kn = (i + 1 > t1) ? (i - t1) : (i + 1);
            ckp0 = cb[kn * HWn + px0];
            ckp1 = cb[kn * HWn + px1];
        }
        if (k == 0) {                           // phase start
            ct0 = cb[t * HWn + px0];
            ct1 = cb[t * HWn + px1];
#pragma unroll
            for (int c = 0; c < 8; ++c) { acc0[c] = 0.f; acc1[c] = 0.f; }
        }

        // ---- coords + gather ds_reads FIRST (banks uncontended)
        const Cw cA = px_coord(ct0, ck0, bx0, by0);
        const Cw cB = px_coord(ct1, ck1, bx1, by1);
        const uint4* fr = (const uint4*)(smem + (i & 1) * CHUNK_B);
        const uint4 a00 = fr[cA.off],      a10 = fr[cA.off + 1];
        const uint4 a01 = fr[cA.off + PW], a11 = fr[cA.off + PW + 1];
        const uint4 b00 = fr[cB.off],      b10 = fr[cB.off + 1];
        const uint4 b01 = fr[cB.off + PW], b11 = fr[cB.off + PW + 1];

        // ---- THEN issue next-frame DMA: its LDS writes land during the
        // MAC phase (banks idle), not during the gather read window.
        if (i < 32) {
            const int kn = (i + 1 > t1) ? (i - t1) : (i + 1);
            STAGE(kn, (i + 1) & 1);             // drains at NEXT barrier
        }

        // ---- MACs (128x v_fma_mix_f32)
        mac8(acc0, a00, cA.w00); mac8(acc0, a10, cA.w10);
        mac8(acc0, a01, cA.w01); mac8(acc0, a11, cA.w11);
        mac8(acc1, b00, cB.w00); mac8(acc1, b10, cB.w10);
        mac8(acc1, b01, cB.w01); mac8(acc1, b11, cB.w11);

        if (k == t) {                           // phase end: write out
            float* op = out + ((size_t)(b * LN + t) * CN + chh * 8) * HWn;
#pragma unroll
            for (int c = 0; c < 8; ++c) {
                op[c * HWn + px0] = acc0[c];
                op[c * HWn + px1] = acc1[c];
            }
        }
    }
#undef STAGE
}

// ---------------------------------------------------------------------------
// Fallback (ws too small / attr fails): direct fp32 gather (proven R1 kernel).
// ---------------------------------------------------------------------------
__global__ __launch_bounds__(256) void gsps_slow(
        const float* __restrict__ flows,
        const float* __restrict__ img,
        float* __restrict__ out) {
    const int bi = blockIdx.x;
    const int tile = bi & 15;
    const int rest = bi >> 4;
    const int t = 31 - (rest & 31);
    const int b = rest >> 5;
    const int p = (tile << 8) + threadIdx.x;
    const int h = p >> 6, w = p & 63;
    const float base_x = ((float)w + 0.5f) * 0.03125f - 1.0f;
    const float base_y = ((float)h + 0.5f) * 0.03125f - 1.0f;
    const float* fl = flows + (size_t)b * (LN * 2 * HWn) + p;

    float ctx = 0.f, cty = 0.f;
    for (int j = 0; j <= t; ++j) { ctx += fl[(2*j)*HWn]; cty += fl[(2*j+1)*HWn]; }

    float acc[16];
#pragma unroll
    for (int c = 0; c < 16; ++c) acc[c] = 0.f;

    float ckx = 0.f, cky = 0.f;
    for (int k = 0; k <= t; ++k) {
        ckx += fl[(2*k)*HWn]; cky += fl[(2*k+1)*HWn];
        float vx = (base_x + (ctx - ckx)) + 1.0f;
        float vy = (base_y + (cty - cky)) + 1.0f;
        float mx = vx - 2.0f * floorf(vx * 0.5f);
        float my = vy - 2.0f * floorf(vy * 0.5f);
        const float ix = ((mx - 1.0f) + 1.0f) * 32.0f - 0.5f;
        const float iy = ((my - 1.0f) + 1.0f) * 32.0f - 0.5f;
        const float x0f = floorf(ix), y0f = floorf(iy);
        const int x0 = (int)x0f, y0 = (int)y0f;
        const float wx1 = ix - x0f, wy1 = iy - y0f;
        const float wx0 = 1.0f - wx1, wy0 = 1.0f - wy1;
        const int x1 = x0 + 1, y1 = y0 + 1;
        const float fx0 = (x0 >= 0) ? 1.0f : 0.0f;
        const float fx1 = (x1 <= 63) ? 1.0f : 0.0f;
        const float fy0 = (y0 >= 0) ? 1.0f : 0.0f;
        const float fy1 = (y1 <= 63) ? 1.0f : 0.0f;
        const int x0c = (x0 < 0) ? 0 : x0, x1c = (x1 > 63) ? 63 : x1;
        const int y0c = (y0 < 0) ? 0 : y0, y1c = (y1 > 63) ? 63 : y1;
        const float w00 = (wx0*wy0)*(fx0*fy0), w10 = (wx1*wy0)*(fx1*fy0);
        const float w01 = (wx0*wy1)*(fx0*fy1), w11 = (wx1*wy1)*(fx1*fy1);
        const float* frm = img + (size_t)(b * LN + k) * FRAME;
        const int i00 = (y0c<<6)+x0c, i10 = (y0c<<6)+x1c;
        const int i01 = (y1c<<6)+x0c, i11 = (y1c<<6)+x1c;
#pragma unroll
        for (int c = 0; c < 16; ++c) {
            const float* pl = frm + c * HWn;
            acc[c] += ((w00*pl[i00] + w10*pl[i10]) + w01*pl[i01]) + w11*pl[i11];
        }
    }
    float* op = out + (size_t)(b * LN + t) * FRAME + p;
#pragma unroll
    for (int c = 0; c < 16; ++c) op[c * HWn] = acc[c];
}

extern "C" void kernel_launch(void* const* d_in, const int* in_sizes, int n_in,
                              void* d_out, int out_size, void* d_ws, size_t ws_size,
                              hipStream_t stream) {
    const float* flows  = (const float*)d_in[0];   // [4,32,2,64,64] f32
    const float* images = (const float*)d_in[1];   // [4,32,16,64,64] f32
    float* out = (float*)d_out;                    // [4,32,16,64,64] f32

    bool fast = (ws_size >= TIMG_BYTES + CUM_BYTES);
    if (fast) {
        hipError_t e = hipFuncSetAttribute(
            reinterpret_cast<const void*>(&gsps_lds),
            hipFuncAttributeMaxDynamicSharedMemorySize, 2 * CHUNK_B);
        if (e != hipSuccess) fast = false;
    }
    if (fast) {
        float4* timg = (float4*)d_ws;
        float2* cumw = (float2*)((char*)d_ws + TIMG_BYTES);
        prep_pad<<<BN * LN * 2, 1024, 0, stream>>>(images, timg);
        prep_cum<<<BN * 16, 256, 0, stream>>>(flows, cumw);
        gsps_lds<<<256, 1024, 2 * CHUNK_B, stream>>>(
            cumw, (const char*)timg, out);
    } else {
        gsps_slow<<<BN * LN * 16, 256, 0, stream>>>(flows, images, out);
    }
}